// Round 1
// baseline (2222.180 us; speedup 1.0000x reference)
//
#include <hip/hip_runtime.h>
#include <hip/hip_bf16.h>
#include <stdint.h>

typedef __attribute__((ext_vector_type(8))) short short8;
typedef __attribute__((ext_vector_type(4))) float f32x4;

#define AS1 __attribute__((address_space(1)))
#define AS3 __attribute__((address_space(3)))

__device__ __forceinline__ short f2bf(float x) {
    __hip_bfloat16 h = __float2bfloat16(x);
    union { __hip_bfloat16 h; short s; } u; u.h = h; return u.s;
}

__device__ __forceinline__ void gload_lds16(const short* g, short* l) {
    __builtin_amdgcn_global_load_lds((const AS1 void*)g, (AS3 void*)l, 16, 0, 0);
}

// ---------------------------------------------------------------------------
// C[m,n] = sum_t sum_k A_t[m,k] * BT_t[n,k]  (+ bias[n])
// A: bf16 row-major [M x K] (lda), BT: bf16 row-major [N x K] (ldb).
// TAPS==3 is the conv path: A is the padded input [2][8194][4096]; per-tile
// row base remaps through the 8194-row padded layout, taps advance one row.
// 128x128 tile, BK=64, 4 waves (2x2), global_load_lds(16B) staging (m97-style).
// ---------------------------------------------------------------------------
template<int TAPS, bool F32OUT>
__global__ __launch_bounds__(256) void gemm_bf16(
    const short* __restrict__ A, int lda, long long tapA,
    const short* __restrict__ BT, int ldb, long long tapB,
    void* __restrict__ Cout, int ldc,
    const float* __restrict__ bias, int K)
{
    __shared__ short As[128 * 64];
    __shared__ short Bs[128 * 64];
    const int tid = threadIdx.x, lane = tid & 63, wid = tid >> 6;
    const int wm = wid >> 1, wn = wid & 1;
    const int m0 = blockIdx.y * 128, n0 = blockIdx.x * 128;
    const size_t arow0 = (TAPS == 3) ? ((size_t)(m0 >> 13) * 8194 + (size_t)(m0 & 8191))
                                     : (size_t)m0;
    const short* Ab = A + arow0 * (size_t)lda;
    const short* Bb = BT + (size_t)n0 * (size_t)ldb;
    const int c15 = lane & 15, g8 = (lane >> 4) * 8, g4 = (lane >> 4) * 4;
    const int srow = lane >> 3, scol = (lane & 7) * 8;

    f32x4 acc[4][4];
    #pragma unroll
    for (int i = 0; i < 4; ++i)
        #pragma unroll
        for (int j = 0; j < 4; ++j)
            acc[i][j] = (f32x4){0.f, 0.f, 0.f, 0.f};

    for (int t = 0; t < TAPS; ++t) {
        const short* At = Ab + (size_t)t * (size_t)tapA;
        const short* Bt = Bb + (size_t)t * (size_t)tapB;
        for (int k0 = 0; k0 < K; k0 += 64) {
            __syncthreads();   // protect LDS from previous iteration's readers
            #pragma unroll
            for (int c = 0; c < 4; ++c) {
                const int ch = wid * 4 + c;           // 16 chunks of 8 rows each
                const int row = ch * 8 + srow;
                gload_lds16(At + (size_t)row * lda + (k0 + scol), As + ch * 512);
                gload_lds16(Bt + (size_t)row * ldb + (k0 + scol), Bs + ch * 512);
            }
            __syncthreads();   // compiler drains vmcnt before s_barrier
            #pragma unroll
            for (int kk = 0; kk < 2; ++kk) {
                short8 af[4], bfv[4];
                #pragma unroll
                for (int mi = 0; mi < 4; ++mi)
                    af[mi] = *(const short8*)(As + (wm * 64 + mi * 16 + c15) * 64 + kk * 32 + g8);
                #pragma unroll
                for (int nj = 0; nj < 4; ++nj)
                    bfv[nj] = *(const short8*)(Bs + (wn * 64 + nj * 16 + c15) * 64 + kk * 32 + g8);
                #pragma unroll
                for (int mi = 0; mi < 4; ++mi)
                    #pragma unroll
                    for (int nj = 0; nj < 4; ++nj)
                        acc[mi][nj] = __builtin_amdgcn_mfma_f32_16x16x32_bf16(
                            af[mi], bfv[nj], acc[mi][nj], 0, 0, 0);
            }
        }
    }

    float bv[4];
    #pragma unroll
    for (int nj = 0; nj < 4; ++nj)
        bv[nj] = bias ? bias[n0 + wn * 64 + nj * 16 + c15] : 0.f;
    #pragma unroll
    for (int mi = 0; mi < 4; ++mi) {
        #pragma unroll
        for (int r = 0; r < 4; ++r) {
            const size_t row = (size_t)m0 + wm * 64 + mi * 16 + g4 + r;
            #pragma unroll
            for (int nj = 0; nj < 4; ++nj) {
                const int col = n0 + wn * 64 + nj * 16 + c15;
                const float v = acc[mi][nj][r] + bv[nj];
                if (F32OUT) ((float*)Cout)[row * (size_t)ldc + col] = v;
                else        ((short*)Cout)[row * (size_t)ldc + col] = f2bf(v);
            }
        }
    }
}

// ---------------------------------------------------------------------------
// Per (head, block) causal attention on 128x128 tiles. qh/kh/vh: [16384][1024]
// bf16 (col = h*64+e). 4 waves x 32 q-rows. All layouts padded to 16B-multiple
// strides (72 / 136 elems) for aligned ds_read_b128 and bank spread.
// ---------------------------------------------------------------------------
__global__ __launch_bounds__(256) void attn_kernel(
    const short* __restrict__ qh, const short* __restrict__ kh,
    const short* __restrict__ vh, short* __restrict__ obuf)
{
    __shared__ __align__(16) char smem[54272];
    short* qs = (short*)smem;                 // [128][72]
    short* ks = (short*)smem + 9216;          // [128][72]
    short* vt = (short*)(smem + 36864);       // [64][136]  (vh transposed)
    short* ps = (short*)smem;                 // [128][136] (reuses qs+ks region)
    short* os = (short*)smem;                 // [128][72]  (reused post-PV)

    const int tid = threadIdx.x, lane = tid & 63, wid = tid >> 6;
    const int h = blockIdx.x, b = blockIdx.y;
    const size_t base = (size_t)b * 128 * 1024 + (size_t)h * 64;

    for (int i = tid; i < 1024; i += 256) {
        const int row = i >> 3, c8 = i & 7;
        const size_t g = base + (size_t)row * 1024 + c8 * 8;
        *(short8*)(qs + row * 72 + c8 * 8) = *(const short8*)(qh + g);
        *(short8*)(ks + row * 72 + c8 * 8) = *(const short8*)(kh + g);
        short8 vv = *(const short8*)(vh + g);
        #pragma unroll
        for (int j = 0; j < 8; ++j) vt[(c8 * 8 + j) * 136 + row] = vv[j];
    }
    __syncthreads();

    const int c15 = lane & 15, g8 = (lane >> 4) * 8, g4 = (lane >> 4) * 4;
    const int r0 = wid * 32;

    // scores = qh @ kh^T  (K=64)
    f32x4 sacc[2][8];
    #pragma unroll
    for (int mi = 0; mi < 2; ++mi)
        #pragma unroll
        for (int nj = 0; nj < 8; ++nj)
            sacc[mi][nj] = (f32x4){0.f, 0.f, 0.f, 0.f};
    #pragma unroll
    for (int kk = 0; kk < 2; ++kk) {
        short8 aq[2];
        #pragma unroll
        for (int mi = 0; mi < 2; ++mi)
            aq[mi] = *(const short8*)(qs + (r0 + mi * 16 + c15) * 72 + kk * 32 + g8);
        #pragma unroll
        for (int nj = 0; nj < 8; ++nj) {
            short8 bk8 = *(const short8*)(ks + (nj * 16 + c15) * 72 + kk * 32 + g8);
            #pragma unroll
            for (int mi = 0; mi < 2; ++mi)
                sacc[mi][nj] = __builtin_amdgcn_mfma_f32_16x16x32_bf16(
                    aq[mi], bk8, sacc[mi][nj], 0, 0, 0);
        }
    }
    __syncthreads();   // everyone done reading qs/ks before ps overwrites them

    // masked softmax, row-parallel across 16-lane groups
    #pragma unroll
    for (int mi = 0; mi < 2; ++mi) {
        #pragma unroll
        for (int r = 0; r < 4; ++r) {
            const int qrow = r0 + mi * 16 + g4 + r;
            float m = -3.0e38f, pv[8];
            #pragma unroll
            for (int nj = 0; nj < 8; ++nj) {
                float s = sacc[mi][nj][r] * 0.125f;      // 1/sqrt(64)
                if (nj * 16 + c15 > qrow) s = -1.0e9f;   // causal mask (ref NEG_INF)
                pv[nj] = s; m = fmaxf(m, s);
            }
            #pragma unroll
            for (int off = 8; off >= 1; off >>= 1) m = fmaxf(m, __shfl_xor(m, off));
            float sum = 0.f;
            #pragma unroll
            for (int nj = 0; nj < 8; ++nj) { float p = __expf(pv[nj] - m); pv[nj] = p; sum += p; }
            #pragma unroll
            for (int off = 8; off >= 1; off >>= 1) sum += __shfl_xor(sum, off);
            const float inv = 1.0f / sum;
            #pragma unroll
            for (int nj = 0; nj < 8; ++nj)
                ps[qrow * 136 + nj * 16 + c15] = f2bf(pv[nj] * inv);
        }
    }
    __syncthreads();

    // o = P @ vh  (K=128)
    f32x4 oacc[2][4];
    #pragma unroll
    for (int mi = 0; mi < 2; ++mi)
        #pragma unroll
        for (int nj = 0; nj < 4; ++nj)
            oacc[mi][nj] = (f32x4){0.f, 0.f, 0.f, 0.f};
    #pragma unroll
    for (int kt = 0; kt < 4; ++kt) {
        short8 ap[2];
        #pragma unroll
        for (int mi = 0; mi < 2; ++mi)
            ap[mi] = *(const short8*)(ps + (r0 + mi * 16 + c15) * 136 + kt * 32 + g8);
        #pragma unroll
        for (int nj = 0; nj < 4; ++nj) {
            short8 bv8 = *(const short8*)(vt + (nj * 16 + c15) * 136 + kt * 32 + g8);
            #pragma unroll
            for (int mi = 0; mi < 2; ++mi)
                oacc[mi][nj] = __builtin_amdgcn_mfma_f32_16x16x32_bf16(
                    ap[mi], bv8, oacc[mi][nj], 0, 0, 0);
        }
    }
    __syncthreads();   // everyone done reading ps/vt

    #pragma unroll
    for (int mi = 0; mi < 2; ++mi)
        #pragma unroll
        for (int r = 0; r < 4; ++r)
            #pragma unroll
            for (int nj = 0; nj < 4; ++nj)
                os[(r0 + mi * 16 + g4 + r) * 72 + nj * 16 + c15] = f2bf(oacc[mi][nj][r]);
    __syncthreads();

    for (int i = tid; i < 1024; i += 256) {
        const int row = i >> 3, c8 = i & 7;
        *(short8*)(obuf + base + (size_t)row * 1024 + c8 * 8) =
            *(const short8*)(os + row * 72 + c8 * 8);
    }
}

// ---------------------------------------------------------------------------
// inputs f32 [2][8192][4096] -> bf16 [2][8194][4096] with zero rows at each
// sequence boundary (kills all conv edge handling).
__global__ void pad_convert_inputs(const float* __restrict__ in, short* __restrict__ out)
{
    const int row = blockIdx.x;                 // [0, 16388)
    const int n = row / 8194, l = row % 8194;
    short* orow = out + (size_t)row * 4096;
    if (l == 0 || l == 8193) {
        for (int i = threadIdx.x; i < 512; i += 256) {
            uint4 z; z.x = z.y = z.z = z.w = 0u;
            *(uint4*)(orow + i * 8) = z;
        }
    } else {
        const float* irow = in + ((size_t)n * 8192 + (l - 1)) * 4096;
        for (int i = threadIdx.x; i < 512; i += 256) {
            float4 a = *(const float4*)(irow + i * 8);
            float4 b = *(const float4*)(irow + i * 8 + 4);
            short8 v;
            v[0] = f2bf(a.x); v[1] = f2bf(a.y); v[2] = f2bf(a.z); v[3] = f2bf(a.w);
            v[4] = f2bf(b.x); v[5] = f2bf(b.y); v[6] = f2bf(b.z); v[7] = f2bf(b.w);
            *(short8*)(orow + i * 8) = v;
        }
    }
}

// out[c][r] = bf16(in[r][c]); R, C multiples of 32.
__global__ void transpose_convert(const float* __restrict__ in, short* __restrict__ out,
                                  int R, int C)
{
    __shared__ float tile[32][33];
    const int tx = threadIdx.x & 31, ty = threadIdx.x >> 5;   // 32 x 8
    const int bx = blockIdx.x * 32, by = blockIdx.y * 32;
    #pragma unroll
    for (int i = 0; i < 32; i += 8)
        tile[ty + i][tx] = in[(size_t)(by + ty + i) * C + bx + tx];
    __syncthreads();
    #pragma unroll
    for (int i = 0; i < 32; i += 8)
        out[(size_t)(bx + ty + i) * R + by + tx] = f2bf(tile[tx][ty + i]);
}

__global__ void convert_bf16(const float* __restrict__ in, short* __restrict__ out, int n8)
{
    const int idx = blockIdx.x * 256 + threadIdx.x;
    if (idx < n8) {
        float4 a = *(const float4*)(in + (size_t)idx * 8);
        float4 b = *(const float4*)(in + (size_t)idx * 8 + 4);
        short8 v;
        v[0] = f2bf(a.x); v[1] = f2bf(a.y); v[2] = f2bf(a.z); v[3] = f2bf(a.w);
        v[4] = f2bf(b.x); v[5] = f2bf(b.y); v[6] = f2bf(b.z); v[7] = f2bf(b.w);
        *(short8*)(out + (size_t)idx * 8) = v;
    }
}

// bfused[j] = proj_b[j] + sum_w bo[w] * proj_w[w][j]
__global__ void fuse_bias(const float* __restrict__ bo, const float* __restrict__ projw,
                          const float* __restrict__ projb, float* __restrict__ outb)
{
    const int j = blockIdx.x * 256 + threadIdx.x;   // 4096
    float s = projb[j];
    for (int w = 0; w < 1024; ++w) s = fmaf(bo[w], projw[(size_t)w * 4096 + j], s);
    outb[j] = s;
}

// ---------------------------------------------------------------------------
extern "C" void kernel_launch(void* const* d_in, const int* in_sizes, int n_in,
                              void* d_out, int out_size, void* d_ws, size_t ws_size,
                              hipStream_t stream)
{
    const float* inputs = (const float*)d_in[0];
    const float* conv_w = (const float*)d_in[1];
    const float* conv_b = (const float*)d_in[2];
    const float* wq     = (const float*)d_in[3];
    const float* bq     = (const float*)d_in[4];
    const float* wk     = (const float*)d_in[5];
    const float* bk     = (const float*)d_in[6];
    const float* wv     = (const float*)d_in[7];
    const float* bv     = (const float*)d_in[8];
    const float* wo     = (const float*)d_in[9];
    const float* bo     = (const float*)d_in[10];
    const float* proj_w = (const float*)d_in[11];
    const float* proj_b = (const float*)d_in[12];

    char* ws = (char*)d_ws;
    short* in_pad = (short*)(ws + 0);             // [2][8194][4096]      134,283,264 B
    short* w_bf   = (short*)(ws + 134283264);     // [3][3072][4096] BT    75,497,472 B
    short* qkv    = (short*)(ws + 209780736);     // [16384][3072]        100,663,296 B
    short* wq_t   = (short*)(ws + 310444032);     // [1024][1024] BT
    short* wk_t   = (short*)(ws + 312541184);
    short* wv_t   = (short*)(ws + 314638336);
    short* wo_bf  = (short*)(ws + 316735488);     // [1024][1024] (= BT for WfT gemm)
    short* proj_t = (short*)(ws + 318832640);     // [4096][1024]
    short* WfT    = (short*)(ws + 327221248);     // [4096][1024] (= BT for final gemm)
    float* bfused = (float*)(ws + 335609856);     // [4096]
    // aliases (stage lifetimes are disjoint, stream-ordered):
    short* qh_buf = (short*)(ws + 0);             // over in_pad (conv already consumed it)
    short* kh_buf = (short*)(ws + 33554432);
    short* vh_buf = (short*)(ws + 67108864);
    short* o_buf  = (short*)(ws + 134283264);     // over w_bf

    dim3 blk(256);

    pad_convert_inputs<<<16388, blk, 0, stream>>>(inputs, in_pad);
    for (int t = 0; t < 3; ++t)
        transpose_convert<<<dim3(96, 128), blk, 0, stream>>>(
            conv_w + (size_t)t * 4096 * 3072, w_bf + (size_t)t * 3072 * 4096, 4096, 3072);
    transpose_convert<<<dim3(32, 32), blk, 0, stream>>>(wq, wq_t, 1024, 1024);
    transpose_convert<<<dim3(32, 32), blk, 0, stream>>>(wk, wk_t, 1024, 1024);
    transpose_convert<<<dim3(32, 32), blk, 0, stream>>>(wv, wv_t, 1024, 1024);
    transpose_convert<<<dim3(128, 32), blk, 0, stream>>>(proj_w, proj_t, 1024, 4096);
    convert_bf16<<<512, blk, 0, stream>>>(wo, wo_bf, 131072);
    fuse_bias<<<16, blk, 0, stream>>>(bo, proj_w, proj_b, bfused);

    // WfT[dm][he] = sum_w proj_t[dm][w] * wo_flat[he][w]
    gemm_bf16<1, false><<<dim3(8, 32), blk, 0, stream>>>(
        proj_t, 1024, 0, wo_bf, 1024, 0, WfT, 1024, nullptr, 1024);
    // conv as 3-tap GEMM: qkv[m][j] (+conv_b)
    gemm_bf16<3, false><<<dim3(24, 128), blk, 0, stream>>>(
        in_pad, 4096, 4096, w_bf, 4096, (long long)3072 * 4096, qkv, 3072, conv_b, 4096);
    // head projections (+bias)
    gemm_bf16<1, false><<<dim3(8, 128), blk, 0, stream>>>(
        qkv + 0,    3072, 0, wq_t, 1024, 0, qh_buf, 1024, bq, 1024);
    gemm_bf16<1, false><<<dim3(8, 128), blk, 0, stream>>>(
        qkv + 1024, 3072, 0, wk_t, 1024, 0, kh_buf, 1024, bk, 1024);
    gemm_bf16<1, false><<<dim3(8, 128), blk, 0, stream>>>(
        qkv + 2048, 3072, 0, wv_t, 1024, 0, vh_buf, 1024, bv, 1024);

    attn_kernel<<<dim3(16, 128), blk, 0, stream>>>(qh_buf, kh_buf, vh_buf, o_buf);

    // out = o @ Wf + bfused   (f32 out)
    gemm_bf16<1, true><<<dim3(32, 128), blk, 0, stream>>>(
        o_buf, 1024, 0, WfT, 1024, 0, d_out, 4096, bfused, 1024);
}

// Round 2
// 1772.947 us; speedup vs baseline: 1.2534x; 1.2534x over previous
//
#include <hip/hip_runtime.h>
#include <hip/hip_bf16.h>
#include <stdint.h>

typedef __attribute__((ext_vector_type(8))) short short8;
typedef __attribute__((ext_vector_type(4))) float f32x4;

#define AS1 __attribute__((address_space(1)))
#define AS3 __attribute__((address_space(3)))

__device__ __forceinline__ short f2bf(float x) {
    __hip_bfloat16 h = __float2bfloat16(x);
    union { __hip_bfloat16 h; short s; } u; u.h = h; return u.s;
}

__device__ __forceinline__ void gload_lds16(const short* g, short* l) {
    __builtin_amdgcn_global_load_lds((const AS1 void*)g, (AS3 void*)l, 16, 0, 0);
}

#define BAR()        asm volatile("s_barrier" ::: "memory")
#define VMCNT_BAR(N) asm volatile("s_waitcnt vmcnt(" #N ")\n\ts_barrier" ::: "memory")

// ---------------------------------------------------------------------------
// 256x256 tile, BK=64, 512 threads = 8 waves (2M x 4N), deep-pipelined.
// LDS: A[2buf][2kh][256][32] + B same = 128 KiB. K-half [256][32] layout:
// 64B row stride -> conflict-free ds_read_b128 (wave hits all 32 banks,
// 8 words each). Staging: tile t+1 issued across the 4 phases of tile t's
// compute (A-kh0, B-kh0, A-kh1, B-kh1), gated by counted vmcnt(4)+barrier
// every 2 phases -- never drain-to-0 in steady state (T3+T4), setprio (T5).
// TAPS==3: conv path; A rows remap through padded [2][8194][4096], tap = +row.
// ---------------------------------------------------------------------------
template<int TAPS, bool F32OUT>
__global__ __launch_bounds__(512, 2) void gemm256(
    const short* __restrict__ A, int lda,
    const short* __restrict__ BT, int ldb, long long tapB,
    void* __restrict__ Cout, int ldc,
    const float* __restrict__ bias, int Ktiles)
{
    __shared__ __align__(16) short As[2 * 2 * 256 * 32];
    __shared__ __align__(16) short Bs[2 * 2 * 256 * 32];
    const int tid = threadIdx.x, lane = tid & 63, wid = tid >> 6;
    const int wm = wid >> 2, wn = wid & 3;
    const int m0 = blockIdx.y * 256, n0 = blockIdx.x * 256;
    const size_t arow0 = (TAPS == 3) ? ((size_t)(m0 >> 13) * 8194 + (size_t)(m0 & 8191))
                                     : (size_t)m0;
    const size_t ldaS = (size_t)lda, ldbS = (size_t)ldb, tapBS = (size_t)tapB;
    const short* Abase0 = A + arow0 * ldaS;
    const short* Bbase0 = BT + (size_t)n0 * ldbS;
    const int c15 = lane & 15, g8 = (lane >> 4) * 8, g4 = (lane >> 4) * 4;
    const int srow = tid >> 2, schunk = (tid & 3) * 8;   // staging: 16B/thread

#define STG_A(u, kh, buf) do { \
    const int tp_ = (TAPS == 3) ? ((u) >> 6) : 0; \
    const int kc_ = (TAPS == 3) ? (((u) & 63) << 6) : ((u) << 6); \
    const short* g_ = Abase0 + (size_t)tp_ * ldaS + kc_ + (kh) * 32 \
                      + (size_t)srow * ldaS + schunk; \
    short* l_ = As + (buf) * 16384 + (kh) * 8192 + wid * 512; \
    gload_lds16(g_, l_); \
    gload_lds16(g_ + 128 * ldaS, l_ + 4096); \
} while (0)

#define STG_B(u, kh, buf) do { \
    const int tp_ = (TAPS == 3) ? ((u) >> 6) : 0; \
    const int kc_ = (TAPS == 3) ? (((u) & 63) << 6) : ((u) << 6); \
    const short* g_ = Bbase0 + (size_t)tp_ * tapBS + kc_ + (kh) * 32 \
                      + (size_t)srow * ldbS + schunk; \
    short* l_ = Bs + (buf) * 16384 + (kh) * 8192 + wid * 512; \
    gload_lds16(g_, l_); \
    gload_lds16(g_ + 128 * ldbS, l_ + 4096); \
} while (0)

#define LDA_(buf, kk, mi) (*(const short8*)(As + (buf) * 16384 + (kk) * 8192 \
                           + (wm * 128 + (mi) * 16 + c15) * 32 + g8))
#define LDB_(buf, kk, nj) (*(const short8*)(Bs + (buf) * 16384 + (kk) * 8192 \
                           + (wn * 64 + (nj) * 16 + c15) * 32 + g8))

#define MFMA8x2(J0, J1) do { \
    __builtin_amdgcn_s_setprio(1); \
    _Pragma("unroll") \
    for (int mi_ = 0; mi_ < 8; ++mi_) \
        acc[mi_][J0] = __builtin_amdgcn_mfma_f32_16x16x32_bf16(af[mi_], b0, acc[mi_][J0], 0, 0, 0); \
    _Pragma("unroll") \
    for (int mi_ = 0; mi_ < 8; ++mi_) \
        acc[mi_][J1] = __builtin_amdgcn_mfma_f32_16x16x32_bf16(af[mi_], b1, acc[mi_][J1], 0, 0, 0); \
    __builtin_amdgcn_s_setprio(0); \
} while (0)

    f32x4 acc[8][4];
    #pragma unroll
    for (int i = 0; i < 8; ++i)
        #pragma unroll
        for (int j = 0; j < 4; ++j)
            acc[i][j] = (f32x4){0.f, 0.f, 0.f, 0.f};

    // prologue: tile 0, issue order = Akh0, Bkh0, Akh1, Bkh1 (8 loads)
    STG_A(0, 0, 0); STG_B(0, 0, 0); STG_A(0, 1, 0); STG_B(0, 1, 0);
    VMCNT_BAR(4);   // kh0 of tile 0 resident; kh1 (4 loads) still in flight

    for (int t = 0; t < Ktiles; ++t) {
        const int c = t & 1, nb = c ^ 1;
        const bool st = (t + 1 < Ktiles);
        const int u = t + 1;
        short8 af[8], b0, b1;

        // ---- ph0: kk=0, nj=0/1 ----
        #pragma unroll
        for (int mi = 0; mi < 8; ++mi) af[mi] = LDA_(c, 0, mi);
        b0 = LDB_(c, 0, 0); b1 = LDB_(c, 0, 1);
        if (st) STG_A(u, 0, nb);
        BAR();
        MFMA8x2(0, 1);
        BAR();

        // ---- ph1: kk=0, nj=2/3 (reuse af) ----
        b0 = LDB_(c, 0, 2); b1 = LDB_(c, 0, 3);
        if (st) STG_B(u, 0, nb);
        if (st) { VMCNT_BAR(4); } else { VMCNT_BAR(0); }   // kh1(t) resident
        MFMA8x2(2, 3);
        BAR();

        // ---- ph2: kk=1, nj=0/1 ----
        #pragma unroll
        for (int mi = 0; mi < 8; ++mi) af[mi] = LDA_(c, 1, mi);
        b0 = LDB_(c, 1, 0); b1 = LDB_(c, 1, 1);
        if (st) STG_A(u, 1, nb);
        BAR();
        MFMA8x2(0, 1);
        BAR();

        // ---- ph3: kk=1, nj=2/3 ----
        b0 = LDB_(c, 1, 2); b1 = LDB_(c, 1, 3);
        if (st) STG_B(u, 1, nb);
        if (st) { VMCNT_BAR(4); } else { VMCNT_BAR(0); }   // kh0(t+1) resident
        MFMA8x2(2, 3);
        BAR();
    }

    float bv[4];
    #pragma unroll
    for (int nj = 0; nj < 4; ++nj)
        bv[nj] = bias ? bias[n0 + wn * 64 + nj * 16 + c15] : 0.f;
    #pragma unroll
    for (int mi = 0; mi < 8; ++mi) {
        #pragma unroll
        for (int r = 0; r < 4; ++r) {
            const size_t row = (size_t)m0 + wm * 128 + mi * 16 + g4 + r;
            #pragma unroll
            for (int nj = 0; nj < 4; ++nj) {
                const int col = n0 + wn * 64 + nj * 16 + c15;
                const float v = acc[mi][nj][r] + bv[nj];
                if (F32OUT) ((float*)Cout)[row * (size_t)ldc + col] = v;
                else        ((short*)Cout)[row * (size_t)ldc + col] = f2bf(v);
            }
        }
    }
#undef STG_A
#undef STG_B
#undef LDA_
#undef LDB_
#undef MFMA8x2
}

// ---------------------------------------------------------------------------
// Per (head, block) causal attention on 128x128 tiles. qh/kh/vh: [16384][1024]
// bf16 (col = h*64+e). 4 waves x 32 q-rows.
// ---------------------------------------------------------------------------
__global__ __launch_bounds__(256) void attn_kernel(
    const short* __restrict__ qh, const short* __restrict__ kh,
    const short* __restrict__ vh, short* __restrict__ obuf)
{
    __shared__ __align__(16) char smem[54272];
    short* qs = (short*)smem;                 // [128][72]
    short* ks = (short*)smem + 9216;          // [128][72]
    short* vt = (short*)(smem + 36864);       // [64][136]  (vh transposed)
    short* ps = (short*)smem;                 // [128][136] (reuses qs+ks region)
    short* os = (short*)smem;                 // [128][72]  (reused post-PV)

    const int tid = threadIdx.x, lane = tid & 63, wid = tid >> 6;
    const int h = blockIdx.x, b = blockIdx.y;
    const size_t base = (size_t)b * 128 * 1024 + (size_t)h * 64;

    for (int i = tid; i < 1024; i += 256) {
        const int row = i >> 3, c8 = i & 7;
        const size_t g = base + (size_t)row * 1024 + c8 * 8;
        *(short8*)(qs + row * 72 + c8 * 8) = *(const short8*)(qh + g);
        *(short8*)(ks + row * 72 + c8 * 8) = *(const short8*)(kh + g);
        short8 vv = *(const short8*)(vh + g);
        #pragma unroll
        for (int j = 0; j < 8; ++j) vt[(c8 * 8 + j) * 136 + row] = vv[j];
    }
    __syncthreads();

    const int c15 = lane & 15, g8 = (lane >> 4) * 8, g4 = (lane >> 4) * 4;
    const int r0 = wid * 32;

    f32x4 sacc[2][8];
    #pragma unroll
    for (int mi = 0; mi < 2; ++mi)
        #pragma unroll
        for (int nj = 0; nj < 8; ++nj)
            sacc[mi][nj] = (f32x4){0.f, 0.f, 0.f, 0.f};
    #pragma unroll
    for (int kk = 0; kk < 2; ++kk) {
        short8 aq[2];
        #pragma unroll
        for (int mi = 0; mi < 2; ++mi)
            aq[mi] = *(const short8*)(qs + (r0 + mi * 16 + c15) * 72 + kk * 32 + g8);
        #pragma unroll
        for (int nj = 0; nj < 8; ++nj) {
            short8 bk8 = *(const short8*)(ks + (nj * 16 + c15) * 72 + kk * 32 + g8);
            #pragma unroll
            for (int mi = 0; mi < 2; ++mi)
                sacc[mi][nj] = __builtin_amdgcn_mfma_f32_16x16x32_bf16(
                    aq[mi], bk8, sacc[mi][nj], 0, 0, 0);
        }
    }
    __syncthreads();

    #pragma unroll
    for (int mi = 0; mi < 2; ++mi) {
        #pragma unroll
        for (int r = 0; r < 4; ++r) {
            const int qrow = r0 + mi * 16 + g4 + r;
            float m = -3.0e38f, pv[8];
            #pragma unroll
            for (int nj = 0; nj < 8; ++nj) {
                float s = sacc[mi][nj][r] * 0.125f;
                if (nj * 16 + c15 > qrow) s = -1.0e9f;
                pv[nj] = s; m = fmaxf(m, s);
            }
            #pragma unroll
            for (int off = 8; off >= 1; off >>= 1) m = fmaxf(m, __shfl_xor(m, off));
            float sum = 0.f;
            #pragma unroll
            for (int nj = 0; nj < 8; ++nj) { float p = __expf(pv[nj] - m); pv[nj] = p; sum += p; }
            #pragma unroll
            for (int off = 8; off >= 1; off >>= 1) sum += __shfl_xor(sum, off);
            const float inv = 1.0f / sum;
            #pragma unroll
            for (int nj = 0; nj < 8; ++nj)
                ps[qrow * 136 + nj * 16 + c15] = f2bf(pv[nj] * inv);
        }
    }
    __syncthreads();

    f32x4 oacc[2][4];
    #pragma unroll
    for (int mi = 0; mi < 2; ++mi)
        #pragma unroll
        for (int nj = 0; nj < 4; ++nj)
            oacc[mi][nj] = (f32x4){0.f, 0.f, 0.f, 0.f};
    #pragma unroll
    for (int kt = 0; kt < 4; ++kt) {
        short8 ap[2];
        #pragma unroll
        for (int mi = 0; mi < 2; ++mi)
            ap[mi] = *(const short8*)(ps + (r0 + mi * 16 + c15) * 136 + kt * 32 + g8);
        #pragma unroll
        for (int nj = 0; nj < 4; ++nj) {
            short8 bv8 = *(const short8*)(vt + (nj * 16 + c15) * 136 + kt * 32 + g8);
            #pragma unroll
            for (int mi = 0; mi < 2; ++mi)
                oacc[mi][nj] = __builtin_amdgcn_mfma_f32_16x16x32_bf16(
                    ap[mi], bv8, oacc[mi][nj], 0, 0, 0);
        }
    }
    __syncthreads();

    #pragma unroll
    for (int mi = 0; mi < 2; ++mi)
        #pragma unroll
        for (int r = 0; r < 4; ++r)
            #pragma unroll
            for (int nj = 0; nj < 4; ++nj)
                os[(r0 + mi * 16 + g4 + r) * 72 + nj * 16 + c15] = f2bf(oacc[mi][nj][r]);
    __syncthreads();

    for (int i = tid; i < 1024; i += 256) {
        const int row = i >> 3, c8 = i & 7;
        *(short8*)(obuf + base + (size_t)row * 1024 + c8 * 8) =
            *(const short8*)(os + row * 72 + c8 * 8);
    }
}

// ---------------------------------------------------------------------------
__global__ void pad_convert_inputs(const float* __restrict__ in, short* __restrict__ out)
{
    const int row = blockIdx.x;                 // [0, 16388)
    const int n = row / 8194, l = row % 8194;
    short* orow = out + (size_t)row * 4096;
    if (l == 0 || l == 8193) {
        for (int i = threadIdx.x; i < 512; i += 256) {
            uint4 z; z.x = z.y = z.z = z.w = 0u;
            *(uint4*)(orow + i * 8) = z;
        }
    } else {
        const float* irow = in + ((size_t)n * 8192 + (l - 1)) * 4096;
        for (int i = threadIdx.x; i < 512; i += 256) {
            float4 a = *(const float4*)(irow + i * 8);
            float4 b = *(const float4*)(irow + i * 8 + 4);
            short8 v;
            v[0] = f2bf(a.x); v[1] = f2bf(a.y); v[2] = f2bf(a.z); v[3] = f2bf(a.w);
            v[4] = f2bf(b.x); v[5] = f2bf(b.y); v[6] = f2bf(b.z); v[7] = f2bf(b.w);
            *(short8*)(orow + i * 8) = v;
        }
    }
}

__global__ void transpose_convert(const float* __restrict__ in, short* __restrict__ out,
                                  int R, int C)
{
    __shared__ float tile[32][33];
    const int tx = threadIdx.x & 31, ty = threadIdx.x >> 5;   // 32 x 8
    const int bx = blockIdx.x * 32, by = blockIdx.y * 32;
    #pragma unroll
    for (int i = 0; i < 32; i += 8)
        tile[ty + i][tx] = in[(size_t)(by + ty + i) * C + bx + tx];
    __syncthreads();
    #pragma unroll
    for (int i = 0; i < 32; i += 8)
        out[(size_t)(bx + ty + i) * R + by + tx] = f2bf(tile[tx][ty + i]);
}

__global__ void convert_bf16(const float* __restrict__ in, short* __restrict__ out, int n8)
{
    const int idx = blockIdx.x * 256 + threadIdx.x;
    if (idx < n8) {
        float4 a = *(const float4*)(in + (size_t)idx * 8);
        float4 b = *(const float4*)(in + (size_t)idx * 8 + 4);
        short8 v;
        v[0] = f2bf(a.x); v[1] = f2bf(a.y); v[2] = f2bf(a.z); v[3] = f2bf(a.w);
        v[4] = f2bf(b.x); v[5] = f2bf(b.y); v[6] = f2bf(b.z); v[7] = f2bf(b.w);
        *(short8*)(out + (size_t)idx * 8) = v;
    }
}

__global__ void fuse_bias(const float* __restrict__ bo, const float* __restrict__ projw,
                          const float* __restrict__ projb, float* __restrict__ outb)
{
    const int j = blockIdx.x * 256 + threadIdx.x;   // 4096
    float s = projb[j];
    for (int w = 0; w < 1024; ++w) s = fmaf(bo[w], projw[(size_t)w * 4096 + j], s);
    outb[j] = s;
}

// ---------------------------------------------------------------------------
extern "C" void kernel_launch(void* const* d_in, const int* in_sizes, int n_in,
                              void* d_out, int out_size, void* d_ws, size_t ws_size,
                              hipStream_t stream)
{
    const float* inputs = (const float*)d_in[0];
    const float* conv_w = (const float*)d_in[1];
    const float* conv_b = (const float*)d_in[2];
    const float* wq     = (const float*)d_in[3];
    const float* bq     = (const float*)d_in[4];
    const float* wk     = (const float*)d_in[5];
    const float* bk     = (const float*)d_in[6];
    const float* wv     = (const float*)d_in[7];
    const float* bv     = (const float*)d_in[8];
    const float* wo     = (const float*)d_in[9];
    const float* bo     = (const float*)d_in[10];
    const float* proj_w = (const float*)d_in[11];
    const float* proj_b = (const float*)d_in[12];

    char* ws = (char*)d_ws;
    short* in_pad = (short*)(ws + 0);             // [2][8194][4096]
    short* w_bf   = (short*)(ws + 134283264);     // [3][3072][4096] BT
    short* qkv    = (short*)(ws + 209780736);     // [16384][3072]
    short* wq_t   = (short*)(ws + 310444032);     // [1024][1024] BT
    short* wk_t   = (short*)(ws + 312541184);
    short* wv_t   = (short*)(ws + 314638336);
    short* wo_bf  = (short*)(ws + 316735488);     // [1024][1024]
    short* proj_t = (short*)(ws + 318832640);     // [4096][1024]
    short* WfT    = (short*)(ws + 327221248);     // [4096][1024]
    float* bfused = (float*)(ws + 335609856);     // [4096]
    short* qh_buf = (short*)(ws + 0);             // over in_pad
    short* kh_buf = (short*)(ws + 33554432);
    short* vh_buf = (short*)(ws + 67108864);
    short* o_buf  = (short*)(ws + 134283264);     // over w_bf

    dim3 blk(256), blk5(512);

    pad_convert_inputs<<<16388, blk, 0, stream>>>(inputs, in_pad);
    for (int t = 0; t < 3; ++t)
        transpose_convert<<<dim3(96, 128), blk, 0, stream>>>(
            conv_w + (size_t)t * 4096 * 3072, w_bf + (size_t)t * 3072 * 4096, 4096, 3072);
    transpose_convert<<<dim3(32, 32), blk, 0, stream>>>(wq, wq_t, 1024, 1024);
    transpose_convert<<<dim3(32, 32), blk, 0, stream>>>(wk, wk_t, 1024, 1024);
    transpose_convert<<<dim3(32, 32), blk, 0, stream>>>(wv, wv_t, 1024, 1024);
    transpose_convert<<<dim3(128, 32), blk, 0, stream>>>(proj_w, proj_t, 1024, 4096);
    convert_bf16<<<512, blk, 0, stream>>>(wo, wo_bf, 131072);
    fuse_bias<<<16, blk, 0, stream>>>(bo, proj_w, proj_b, bfused);

    // WfT[dm][he] = sum_w proj_t[dm][w] * wo_flat[he][w]
    gemm256<1, false><<<dim3(4, 16), blk5, 0, stream>>>(
        proj_t, 1024, wo_bf, 1024, 0, WfT, 1024, nullptr, 16);
    // conv as 3-tap GEMM
    gemm256<3, false><<<dim3(12, 64), blk5, 0, stream>>>(
        in_pad, 4096, w_bf, 4096, (long long)3072 * 4096, qkv, 3072, conv_b, 192);
    // head projections
    gemm256<1, false><<<dim3(4, 64), blk5, 0, stream>>>(
        qkv + 0,    3072, wq_t, 1024, 0, qh_buf, 1024, bq, 16);
    gemm256<1, false><<<dim3(4, 64), blk5, 0, stream>>>(
        qkv + 1024, 3072, wk_t, 1024, 0, kh_buf, 1024, bk, 16);
    gemm256<1, false><<<dim3(4, 64), blk5, 0, stream>>>(
        qkv + 2048, 3072, wv_t, 1024, 0, vh_buf, 1024, bv, 16);

    attn_kernel<<<dim3(16, 128), blk, 0, stream>>>(qh_buf, kh_buf, vh_buf, o_buf);

    // out = o @ Wf + bfused   (f32 out)
    gemm256<1, true><<<dim3(16, 64), blk5, 0, stream>>>(
        o_buf, 1024, WfT, 1024, 0, d_out, 4096, bfused, 16);
}

// Round 4
// 1728.570 us; speedup vs baseline: 1.2856x; 1.0257x over previous
//
#include <hip/hip_runtime.h>
#include <hip/hip_bf16.h>
#include <stdint.h>

typedef __attribute__((ext_vector_type(8))) short short8;
typedef __attribute__((ext_vector_type(4))) float f32x4;

#define AS1 __attribute__((address_space(1)))
#define AS3 __attribute__((address_space(3)))

__device__ __forceinline__ short f2bf(float x) {
    __hip_bfloat16 h = __float2bfloat16(x);
    union { __hip_bfloat16 h; short s; } u; u.h = h; return u.s;
}

__device__ __forceinline__ void gload_lds16(const short* g, short* l) {
    __builtin_amdgcn_global_load_lds((const AS1 void*)g, (AS3 void*)l, 16, 0, 0);
}

#define BAR()        asm volatile("s_barrier" ::: "memory")
#define VMCNT_BAR(N) asm volatile("s_waitcnt vmcnt(" #N ")\n\ts_barrier" ::: "memory")

// ---------------------------------------------------------------------------
// 256x256 tile, BK=64, 512 threads = 8 waves (2M x 4N), deep-pipelined
// (T3+T4 counted vmcnt, T5 setprio). LDS: A[2buf][2kh][256][32] + B = 128 KiB.
// T2 swizzle: 16B-chunk slot ^= (row>>1)&3. Within an 8-lane cycle group
// (8 consecutive rows, fixed chunk) the (row&1, quad) pairs are all distinct
// -> conflict-free (old layout was 4-way). Read-side XOR term ((c15>>1)&3) is
// a per-thread constant; staging keeps linear global_load_lds dest and
// pre-swizzles the GLOBAL source chunk by the same involution (rule #21).
// TAPS==3: conv path; A rows remap through padded [2][8194][4096], tap = +row.
// ---------------------------------------------------------------------------
template<int TAPS, bool F32OUT>
__global__ __launch_bounds__(512, 2) void gemm256(
    const short* __restrict__ A, int lda,
    const short* __restrict__ BT, int ldb, long long tapB,
    void* __restrict__ Cout, int ldc,
    const float* __restrict__ bias, int Ktiles)
{
    __shared__ __align__(16) short As[2 * 2 * 256 * 32];
    __shared__ __align__(16) short Bs[2 * 2 * 256 * 32];
    const int tid = threadIdx.x, lane = tid & 63, wid = tid >> 6;
    const int wm = wid >> 2, wn = wid & 3;
    const int m0 = blockIdx.y * 256, n0 = blockIdx.x * 256;
    const size_t arow0 = (TAPS == 3) ? ((size_t)(m0 >> 13) * 8194 + (size_t)(m0 & 8191))
                                     : (size_t)m0;
    const size_t ldaS = (size_t)lda, ldbS = (size_t)ldb, tapBS = (size_t)tapB;
    const short* Abase0 = A + arow0 * ldaS;
    const short* Bbase0 = BT + (size_t)n0 * ldbS;
    const int c15 = lane & 15, g4 = (lane >> 4) * 4;
    // T2 read-side: swizzled 16B-chunk offset (elements), per-thread constant
    const int swz = ((lane >> 4) ^ ((c15 >> 1) & 3)) * 8;
    // staging: row = tid>>2, slot = tid&3 -> load global chunk slot^((row>>1)&3)
    const int srow = tid >> 2;
    const int schunk = (((tid & 3) ^ ((tid >> 3) & 3)) * 8);

#define STG_A(u, kh, buf) do { \
    const int tp_ = (TAPS == 3) ? ((u) >> 6) : 0; \
    const int kc_ = (TAPS == 3) ? (((u) & 63) << 6) : ((u) << 6); \
    const short* g_ = Abase0 + (size_t)tp_ * ldaS + kc_ + (kh) * 32 \
                      + (size_t)srow * ldaS + schunk; \
    short* l_ = As + (buf) * 16384 + (kh) * 8192 + wid * 512; \
    gload_lds16(g_, l_); \
    gload_lds16(g_ + 128 * ldaS, l_ + 4096); \
} while (0)

#define STG_B(u, kh, buf) do { \
    const int tp_ = (TAPS == 3) ? ((u) >> 6) : 0; \
    const int kc_ = (TAPS == 3) ? (((u) & 63) << 6) : ((u) << 6); \
    const short* g_ = Bbase0 + (size_t)tp_ * tapBS + kc_ + (kh) * 32 \
                      + (size_t)srow * ldbS + schunk; \
    short* l_ = Bs + (buf) * 16384 + (kh) * 8192 + wid * 512; \
    gload_lds16(g_, l_); \
    gload_lds16(g_ + 128 * ldbS, l_ + 4096); \
} while (0)

#define LDA_(buf, kk, mi) (*(const short8*)(As + (buf) * 16384 + (kk) * 8192 \
                           + (wm * 128 + (mi) * 16 + c15) * 32 + swz))
#define LDB_(buf, kk, nj) (*(const short8*)(Bs + (buf) * 16384 + (kk) * 8192 \
                           + (wn * 64 + (nj) * 16 + c15) * 32 + swz))

#define MFMA8x2(J0, J1) do { \
    __builtin_amdgcn_s_setprio(1); \
    _Pragma("unroll") \
    for (int mi_ = 0; mi_ < 8; ++mi_) \
        acc[mi_][J0] = __builtin_amdgcn_mfma_f32_16x16x32_bf16(af[mi_], b0, acc[mi_][J0], 0, 0, 0); \
    _Pragma("unroll") \
    for (int mi_ = 0; mi_ < 8; ++mi_) \
        acc[mi_][J1] = __builtin_amdgcn_mfma_f32_16x16x32_bf16(af[mi_], b1, acc[mi_][J1], 0, 0, 0); \
    __builtin_amdgcn_s_setprio(0); \
} while (0)

    f32x4 acc[8][4];
    #pragma unroll
    for (int i = 0; i < 8; ++i)
        #pragma unroll
        for (int j = 0; j < 4; ++j)
            acc[i][j] = (f32x4){0.f, 0.f, 0.f, 0.f};

    // prologue: tile 0, issue order = Akh0, Bkh0, Akh1, Bkh1 (8 loads)
    STG_A(0, 0, 0); STG_B(0, 0, 0); STG_A(0, 1, 0); STG_B(0, 1, 0);
    VMCNT_BAR(4);   // kh0 of tile 0 resident; kh1 (4 loads) still in flight

    for (int t = 0; t < Ktiles; ++t) {
        const int c = t & 1, nb = c ^ 1;
        const bool st = (t + 1 < Ktiles);
        const int u = t + 1;
        short8 af[8], b0, b1;

        // ---- ph0: kk=0, nj=0/1 ----
        #pragma unroll
        for (int mi = 0; mi < 8; ++mi) af[mi] = LDA_(c, 0, mi);
        b0 = LDB_(c, 0, 0); b1 = LDB_(c, 0, 1);
        if (st) STG_A(u, 0, nb);
        BAR();
        MFMA8x2(0, 1);
        BAR();

        // ---- ph1: kk=0, nj=2/3 (reuse af) ----
        b0 = LDB_(c, 0, 2); b1 = LDB_(c, 0, 3);
        if (st) STG_B(u, 0, nb);
        if (st) { VMCNT_BAR(4); } else { VMCNT_BAR(0); }   // kh1(t) resident
        MFMA8x2(2, 3);
        BAR();

        // ---- ph2: kk=1, nj=0/1 ----
        #pragma unroll
        for (int mi = 0; mi < 8; ++mi) af[mi] = LDA_(c, 1, mi);
        b0 = LDB_(c, 1, 0); b1 = LDB_(c, 1, 1);
        if (st) STG_A(u, 1, nb);
        BAR();
        MFMA8x2(0, 1);
        BAR();

        // ---- ph3: kk=1, nj=2/3 ----
        b0 = LDB_(c, 1, 2); b1 = LDB_(c, 1, 3);
        if (st) STG_B(u, 1, nb);
        if (st) { VMCNT_BAR(4); } else { VMCNT_BAR(0); }   // kh0(t+1) resident
        MFMA8x2(2, 3);
        BAR();
    }

    float bv[4];
    #pragma unroll
    for (int nj = 0; nj < 4; ++nj)
        bv[nj] = bias ? bias[n0 + wn * 64 + nj * 16 + c15] : 0.f;
    #pragma unroll
    for (int mi = 0; mi < 8; ++mi) {
        #pragma unroll
        for (int r = 0; r < 4; ++r) {
            const size_t row = (size_t)m0 + wm * 128 + mi * 16 + g4 + r;
            #pragma unroll
            for (int nj = 0; nj < 4; ++nj) {
                const int col = n0 + wn * 64 + nj * 16 + c15;
                const float v = acc[mi][nj][r] + bv[nj];
                if (F32OUT) ((float*)Cout)[row * (size_t)ldc + col] = v;
                else        ((short*)Cout)[row * (size_t)ldc + col] = f2bf(v);
            }
        }
    }
#undef STG_A
#undef STG_B
#undef LDA_
#undef LDB_
#undef MFMA8x2
}

// ---------------------------------------------------------------------------
// Per (head, block) causal attention on 128x128 tiles. qh/kh/vh: [16384][1024]
// bf16 (col = h*64+e). 4 waves x 32 q-rows.
// ---------------------------------------------------------------------------
__global__ __launch_bounds__(256) void attn_kernel(
    const short* __restrict__ qh, const short* __restrict__ kh,
    const short* __restrict__ vh, short* __restrict__ obuf)
{
    __shared__ __align__(16) char smem[54272];
    short* qs = (short*)smem;                 // [128][72]
    short* ks = (short*)smem + 9216;          // [128][72]
    short* vt = (short*)(smem + 36864);       // [64][136]  (vh transposed)
    short* ps = (short*)smem;                 // [128][136] (reuses qs+ks region)
    short* os = (short*)smem;                 // [128][72]  (reused post-PV)

    const int tid = threadIdx.x, lane = tid & 63, wid = tid >> 6;
    const int h = blockIdx.x, b = blockIdx.y;
    const size_t base = (size_t)b * 128 * 1024 + (size_t)h * 64;

    for (int i = tid; i < 1024; i += 256) {
        const int row = i >> 3, c8 = i & 7;
        const size_t g = base + (size_t)row * 1024 + c8 * 8;
        *(short8*)(qs + row * 72 + c8 * 8) = *(const short8*)(qh + g);
        *(short8*)(ks + row * 72 + c8 * 8) = *(const short8*)(kh + g);
        short8 vv = *(const short8*)(vh + g);
        #pragma unroll
        for (int j = 0; j < 8; ++j) vt[(c8 * 8 + j) * 136 + row] = vv[j];
    }
    __syncthreads();

    const int c15 = lane & 15, g8 = (lane >> 4) * 8, g4 = (lane >> 4) * 4;
    const int r0 = wid * 32;

    f32x4 sacc[2][8];
    #pragma unroll
    for (int mi = 0; mi < 2; ++mi)
        #pragma unroll
        for (int nj = 0; nj < 8; ++nj)
            sacc[mi][nj] = (f32x4){0.f, 0.f, 0.f, 0.f};
    #pragma unroll
    for (int kk = 0; kk < 2; ++kk) {
        short8 aq[2];
        #pragma unroll
        for (int mi = 0; mi < 2; ++mi)
            aq[mi] = *(const short8*)(qs + (r0 + mi * 16 + c15) * 72 + kk * 32 + g8);
        #pragma unroll
        for (int nj = 0; nj < 8; ++nj) {
            short8 bk8 = *(const short8*)(ks + (nj * 16 + c15) * 72 + kk * 32 + g8);
            #pragma unroll
            for (int mi = 0; mi < 2; ++mi)
                sacc[mi][nj] = __builtin_amdgcn_mfma_f32_16x16x32_bf16(
                    aq[mi], bk8, sacc[mi][nj], 0, 0, 0);
        }
    }
    __syncthreads();

    #pragma unroll
    for (int mi = 0; mi < 2; ++mi) {
        #pragma unroll
        for (int r = 0; r < 4; ++r) {
            const int qrow = r0 + mi * 16 + g4 + r;
            float m = -3.0e38f, pv[8];
            #pragma unroll
            for (int nj = 0; nj < 8; ++nj) {
                float s = sacc[mi][nj][r] * 0.125f;
                if (nj * 16 + c15 > qrow) s = -1.0e9f;
                pv[nj] = s; m = fmaxf(m, s);
            }
            #pragma unroll
            for (int off = 8; off >= 1; off >>= 1) m = fmaxf(m, __shfl_xor(m, off));
            float sum = 0.f;
            #pragma unroll
            for (int nj = 0; nj < 8; ++nj) { float p = __expf(pv[nj] - m); pv[nj] = p; sum += p; }
            #pragma unroll
            for (int off = 8; off >= 1; off >>= 1) sum += __shfl_xor(sum, off);
            const float inv = 1.0f / sum;
            #pragma unroll
            for (int nj = 0; nj < 8; ++nj)
                ps[qrow * 136 + nj * 16 + c15] = f2bf(pv[nj] * inv);
        }
    }
    __syncthreads();

    f32x4 oacc[2][4];
    #pragma unroll
    for (int mi = 0; mi < 2; ++mi)
        #pragma unroll
        for (int nj = 0; nj < 4; ++nj)
            oacc[mi][nj] = (f32x4){0.f, 0.f, 0.f, 0.f};
    #pragma unroll
    for (int kt = 0; kt < 4; ++kt) {
        short8 ap[2];
        #pragma unroll
        for (int mi = 0; mi < 2; ++mi)
            ap[mi] = *(const short8*)(ps + (r0 + mi * 16 + c15) * 136 + kt * 32 + g8);
        #pragma unroll
        for (int nj = 0; nj < 4; ++nj) {
            short8 bv8 = *(const short8*)(vt + (nj * 16 + c15) * 136 + kt * 32 + g8);
            #pragma unroll
            for (int mi = 0; mi < 2; ++mi)
                oacc[mi][nj] = __builtin_amdgcn_mfma_f32_16x16x32_bf16(
                    ap[mi], bv8, oacc[mi][nj], 0, 0, 0);
        }
    }
    __syncthreads();

    #pragma unroll
    for (int mi = 0; mi < 2; ++mi)
        #pragma unroll
        for (int r = 0; r < 4; ++r)
            #pragma unroll
            for (int nj = 0; nj < 4; ++nj)
                os[(r0 + mi * 16 + g4 + r) * 72 + nj * 16 + c15] = f2bf(oacc[mi][nj][r]);
    __syncthreads();

    for (int i = tid; i < 1024; i += 256) {
        const int row = i >> 3, c8 = i & 7;
        *(short8*)(obuf + base + (size_t)row * 1024 + c8 * 8) =
            *(const short8*)(os + row * 72 + c8 * 8);
    }
}

// ---------------------------------------------------------------------------
__global__ void pad_convert_inputs(const float* __restrict__ in, short* __restrict__ out)
{
    const int row = blockIdx.x;                 // [0, 16388)
    const int n = row / 8194, l = row % 8194;
    short* orow = out + (size_t)row * 4096;
    if (l == 0 || l == 8193) {
        for (int i = threadIdx.x; i < 512; i += 256) {
            uint4 z; z.x = z.y = z.z = z.w = 0u;
            *(uint4*)(orow + i * 8) = z;
        }
    } else {
        const float* irow = in + ((size_t)n * 8192 + (l - 1)) * 4096;
        for (int i = threadIdx.x; i < 512; i += 256) {
            float4 a = *(const float4*)(irow + i * 8);
            float4 b = *(const float4*)(irow + i * 8 + 4);
            short8 v;
            v[0] = f2bf(a.x); v[1] = f2bf(a.y); v[2] = f2bf(a.z); v[3] = f2bf(a.w);
            v[4] = f2bf(b.x); v[5] = f2bf(b.y); v[6] = f2bf(b.z); v[7] = f2bf(b.w);
            *(short8*)(orow + i * 8) = v;
        }
    }
}

__global__ void transpose_convert(const float* __restrict__ in, short* __restrict__ out,
                                  int R, int C)
{
    __shared__ float tile[32][33];
    const int tx = threadIdx.x & 31, ty = threadIdx.x >> 5;   // 32 x 8
    const int bx = blockIdx.x * 32, by = blockIdx.y * 32;
    #pragma unroll
    for (int i = 0; i < 32; i += 8)
        tile[ty + i][tx] = in[(size_t)(by + ty + i) * C + bx + tx];
    __syncthreads();
    #pragma unroll
    for (int i = 0; i < 32; i += 8)
        out[(size_t)(bx + ty + i) * R + by + tx] = f2bf(tile[tx][ty + i]);
}

__global__ void convert_bf16(const float* __restrict__ in, short* __restrict__ out, int n8)
{
    const int idx = blockIdx.x * 256 + threadIdx.x;
    if (idx < n8) {
        float4 a = *(const float4*)(in + (size_t)idx * 8);
        float4 b = *(const float4*)(in + (size_t)idx * 8 + 4);
        short8 v;
        v[0] = f2bf(a.x); v[1] = f2bf(a.y); v[2] = f2bf(a.z); v[3] = f2bf(a.w);
        v[4] = f2bf(b.x); v[5] = f2bf(b.y); v[6] = f2bf(b.z); v[7] = f2bf(b.w);
        *(short8*)(out + (size_t)idx * 8) = v;
    }
}

__global__ void fuse_bias(const float* __restrict__ bo, const float* __restrict__ projw,
                          const float* __restrict__ projb, float* __restrict__ outb)
{
    const int j = blockIdx.x * 256 + threadIdx.x;   // 4096
    float s = projb[j];
    for (int w = 0; w < 1024; ++w) s = fmaf(bo[w], projw[(size_t)w * 4096 + j], s);
    outb[j] = s;
}

// ---------------------------------------------------------------------------
extern "C" void kernel_launch(void* const* d_in, const int* in_sizes, int n_in,
                              void* d_out, int out_size, void* d_ws, size_t ws_size,
                              hipStream_t stream)
{
    const float* inputs = (const float*)d_in[0];
    const float* conv_w = (const float*)d_in[1];
    const float* conv_b = (const float*)d_in[2];
    const float* wq     = (const float*)d_in[3];
    const float* bq     = (const float*)d_in[4];
    const float* wk     = (const float*)d_in[5];
    const float* bk     = (const float*)d_in[6];
    const float* wv     = (const float*)d_in[7];
    const float* bv     = (const float*)d_in[8];
    const float* wo     = (const float*)d_in[9];
    const float* bo     = (const float*)d_in[10];
    const float* proj_w = (const float*)d_in[11];
    const float* proj_b = (const float*)d_in[12];

    char* ws = (char*)d_ws;
    short* in_pad = (short*)(ws + 0);             // [2][8194][4096]
    short* w_bf   = (short*)(ws + 134283264);     // [3][3072][4096] BT
    short* qkv    = (short*)(ws + 209780736);     // [16384][3072]
    short* wq_t   = (short*)(ws + 310444032);     // [1024][1024] BT
    short* wk_t   = (short*)(ws + 312541184);
    short* wv_t   = (short*)(ws + 314638336);
    short* wo_bf  = (short*)(ws + 316735488);     // [1024][1024]
    short* proj_t = (short*)(ws + 318832640);     // [4096][1024]
    short* WfT    = (short*)(ws + 327221248);     // [4096][1024]
    float* bfused = (float*)(ws + 335609856);     // [4096]
    short* qh_buf = (short*)(ws + 0);             // over in_pad
    short* kh_buf = (short*)(ws + 33554432);
    short* vh_buf = (short*)(ws + 67108864);
    short* o_buf  = (short*)(ws + 134283264);     // over w_bf

    dim3 blk(256), blk5(512);

    pad_convert_inputs<<<16388, blk, 0, stream>>>(inputs, in_pad);
    for (int t = 0; t < 3; ++t)
        transpose_convert<<<dim3(96, 128), blk, 0, stream>>>(
            conv_w + (size_t)t * 4096 * 3072, w_bf + (size_t)t * 3072 * 4096, 4096, 3072);
    transpose_convert<<<dim3(32, 32), blk, 0, stream>>>(wq, wq_t, 1024, 1024);
    transpose_convert<<<dim3(32, 32), blk, 0, stream>>>(wk, wk_t, 1024, 1024);
    transpose_convert<<<dim3(32, 32), blk, 0, stream>>>(wv, wv_t, 1024, 1024);
    transpose_convert<<<dim3(128, 32), blk, 0, stream>>>(proj_w, proj_t, 1024, 4096);
    convert_bf16<<<512, blk, 0, stream>>>(wo, wo_bf, 131072);
    fuse_bias<<<16, blk, 0, stream>>>(bo, proj_w, proj_b, bfused);

    // WfT[dm][he] = sum_w proj_t[dm][w] * wo_flat[he][w]
    gemm256<1, false><<<dim3(4, 16), blk5, 0, stream>>>(
        proj_t, 1024, wo_bf, 1024, 0, WfT, 1024, nullptr, 16);
    // conv as 3-tap GEMM
    gemm256<3, false><<<dim3(12, 64), blk5, 0, stream>>>(
        in_pad, 4096, w_bf, 4096, (long long)3072 * 4096, qkv, 3072, conv_b, 192);
    // head projections
    gemm256<1, false><<<dim3(4, 64), blk5, 0, stream>>>(
        qkv + 0,    3072, wq_t, 1024, 0, qh_buf, 1024, bq, 16);
    gemm256<1, false><<<dim3(4, 64), blk5, 0, stream>>>(
        qkv + 1024, 3072, wk_t, 1024, 0, kh_buf, 1024, bk, 16);
    gemm256<1, false><<<dim3(4, 64), blk5, 0, stream>>>(
        qkv + 2048, 3072, wv_t, 1024, 0, vh_buf, 1024, bv, 16);

    attn_kernel<<<dim3(16, 128), blk, 0, stream>>>(qh_buf, kh_buf, vh_buf, o_buf);

    // out = o @ Wf + bfused   (f32 out)
    gemm256<1, true><<<dim3(16, 64), blk5, 0, stream>>>(
        o_buf, 1024, WfT, 1024, 0, d_out, 4096, bfused, 16);
}

// Round 5
// 1672.305 us; speedup vs baseline: 1.3288x; 1.0336x over previous
//
#include <hip/hip_runtime.h>
#include <hip/hip_bf16.h>
#include <stdint.h>

typedef __attribute__((ext_vector_type(8))) short short8;
typedef __attribute__((ext_vector_type(4))) float f32x4;

#define AS1 __attribute__((address_space(1)))
#define AS3 __attribute__((address_space(3)))

__device__ __forceinline__ short f2bf(float x) {
    __hip_bfloat16 h = __float2bfloat16(x);
    union { __hip_bfloat16 h; short s; } u; u.h = h; return u.s;
}

__device__ __forceinline__ void gload_lds16(const short* g, short* l) {
    __builtin_amdgcn_global_load_lds((const AS1 void*)g, (AS3 void*)l, 16, 0, 0);
}

#define BAR()        asm volatile("s_barrier" ::: "memory")
#define VMCNT_BAR(N) asm volatile("s_waitcnt vmcnt(" #N ")\n\ts_barrier" ::: "memory")

// ---------------------------------------------------------------------------
// 256x256 tile, BK=64, 512 threads = 8 waves (2M x 4N), deep-pipelined
// (T3+T4 counted vmcnt, T5 setprio). LDS: A[2buf][2kh][256][32] + B = 128 KiB.
// T2 swizzle: 16B-chunk slot ^= (row>>1)&3 (conflict-free, measured 0 in r4).
// Phases split on mi (m201 balance): reads/phase = 8/4/8/4 (was 10/2/10/2),
// so each phase's LDS burst (<=48 KB ~ 375 cy) fits under the previous MFMA
// cluster's ~620 cy pipe-drain shadow. b-fragments reused across mi-phases.
// TAPS==3: conv path; A rows remap through padded [2][8194][4096], tap = +row.
// ---------------------------------------------------------------------------
template<int TAPS, bool F32OUT>
__global__ __launch_bounds__(512, 2) void gemm256(
    const short* __restrict__ A, int lda,
    const short* __restrict__ BT, int ldb, long long tapB,
    void* __restrict__ Cout, int ldc,
    const float* __restrict__ bias, int Ktiles)
{
    __shared__ __align__(16) short As[2 * 2 * 256 * 32];
    __shared__ __align__(16) short Bs[2 * 2 * 256 * 32];
    const int tid = threadIdx.x, lane = tid & 63, wid = tid >> 6;
    const int wm = wid >> 2, wn = wid & 3;
    const int m0 = blockIdx.y * 256, n0 = blockIdx.x * 256;
    const size_t arow0 = (TAPS == 3) ? ((size_t)(m0 >> 13) * 8194 + (size_t)(m0 & 8191))
                                     : (size_t)m0;
    const size_t ldaS = (size_t)lda, ldbS = (size_t)ldb, tapBS = (size_t)tapB;
    const short* Abase0 = A + arow0 * ldaS;
    const short* Bbase0 = BT + (size_t)n0 * ldbS;
    const int c15 = lane & 15, g4 = (lane >> 4) * 4;
    // T2 read-side: swizzled 16B-chunk offset (elements), per-thread constant
    const int swz = ((lane >> 4) ^ ((c15 >> 1) & 3)) * 8;
    // staging: row = tid>>2, slot = tid&3 -> load global chunk slot^((row>>1)&3)
    const int srow = tid >> 2;
    const int schunk = (((tid & 3) ^ ((tid >> 3) & 3)) * 8);

#define STG_A(u, kh, buf) do { \
    const int tp_ = (TAPS == 3) ? ((u) >> 6) : 0; \
    const int kc_ = (TAPS == 3) ? (((u) & 63) << 6) : ((u) << 6); \
    const short* g_ = Abase0 + (size_t)tp_ * ldaS + kc_ + (kh) * 32 \
                      + (size_t)srow * ldaS + schunk; \
    short* l_ = As + (buf) * 16384 + (kh) * 8192 + wid * 512; \
    gload_lds16(g_, l_); \
    gload_lds16(g_ + 128 * ldaS, l_ + 4096); \
} while (0)

#define STG_B(u, kh, buf) do { \
    const int tp_ = (TAPS == 3) ? ((u) >> 6) : 0; \
    const int kc_ = (TAPS == 3) ? (((u) & 63) << 6) : ((u) << 6); \
    const short* g_ = Bbase0 + (size_t)tp_ * tapBS + kc_ + (kh) * 32 \
                      + (size_t)srow * ldbS + schunk; \
    short* l_ = Bs + (buf) * 16384 + (kh) * 8192 + wid * 512; \
    gload_lds16(g_, l_); \
    gload_lds16(g_ + 128 * ldbS, l_ + 4096); \
} while (0)

#define LDA_(buf, kk, mi) (*(const short8*)(As + (buf) * 16384 + (kk) * 8192 \
                           + (wm * 128 + (mi) * 16 + c15) * 32 + swz))
#define LDB_(buf, kk, nj) (*(const short8*)(Bs + (buf) * 16384 + (kk) * 8192 \
                           + (wn * 64 + (nj) * 16 + c15) * 32 + swz))

// 16 MFMA: af[0..3] x bf4[0..3] -> acc[MB..MB+3][0..3]
#define MFMA4x4(MB) do { \
    __builtin_amdgcn_s_setprio(1); \
    _Pragma("unroll") \
    for (int mi_ = 0; mi_ < 4; ++mi_) \
        _Pragma("unroll") \
        for (int nj_ = 0; nj_ < 4; ++nj_) \
            acc[(MB) + mi_][nj_] = __builtin_amdgcn_mfma_f32_16x16x32_bf16( \
                af[mi_], bf4[nj_], acc[(MB) + mi_][nj_], 0, 0, 0); \
    __builtin_amdgcn_s_setprio(0); \
} while (0)

    f32x4 acc[8][4];
    #pragma unroll
    for (int i = 0; i < 8; ++i)
        #pragma unroll
        for (int j = 0; j < 4; ++j)
            acc[i][j] = (f32x4){0.f, 0.f, 0.f, 0.f};

    // prologue: tile 0, issue order = Akh0, Bkh0, Akh1, Bkh1 (8 loads)
    STG_A(0, 0, 0); STG_B(0, 0, 0); STG_A(0, 1, 0); STG_B(0, 1, 0);
    VMCNT_BAR(4);   // kh0 of tile 0 resident; kh1 (4 loads) still in flight

    for (int t = 0; t < Ktiles; ++t) {
        const int c = t & 1, nb = c ^ 1;
        const bool st = (t + 1 < Ktiles);
        const int u = t + 1;
        short8 af[4], bf4[4];

        // ---- ph0: kk=0, mi 0-3 (+ all 4 b) ----
        #pragma unroll
        for (int mi = 0; mi < 4; ++mi) af[mi] = LDA_(c, 0, mi);
        #pragma unroll
        for (int nj = 0; nj < 4; ++nj) bf4[nj] = LDB_(c, 0, nj);
        if (st) STG_A(u, 0, nb);
        BAR();
        MFMA4x4(0);
        BAR();

        // ---- ph1: kk=0, mi 4-7 (reuse bf4) ----
        #pragma unroll
        for (int mi = 0; mi < 4; ++mi) af[mi] = LDA_(c, 0, 4 + mi);
        if (st) STG_B(u, 0, nb);
        if (st) { VMCNT_BAR(4); } else { VMCNT_BAR(0); }   // kh1(t) resident
        MFMA4x4(4);
        BAR();

        // ---- ph2: kk=1, mi 0-3 (+ all 4 b) ----
        #pragma unroll
        for (int mi = 0; mi < 4; ++mi) af[mi] = LDA_(c, 1, mi);
        #pragma unroll
        for (int nj = 0; nj < 4; ++nj) bf4[nj] = LDB_(c, 1, nj);
        if (st) STG_A(u, 1, nb);
        BAR();
        MFMA4x4(0);
        BAR();

        // ---- ph3: kk=1, mi 4-7 (reuse bf4) ----
        #pragma unroll
        for (int mi = 0; mi < 4; ++mi) af[mi] = LDA_(c, 1, 4 + mi);
        if (st) STG_B(u, 1, nb);
        if (st) { VMCNT_BAR(4); } else { VMCNT_BAR(0); }   // kh0(t+1) resident
        MFMA4x4(4);
        BAR();
    }

    float bv[4];
    #pragma unroll
    for (int nj = 0; nj < 4; ++nj)
        bv[nj] = bias ? bias[n0 + wn * 64 + nj * 16 + c15] : 0.f;
    #pragma unroll
    for (int mi = 0; mi < 8; ++mi) {
        #pragma unroll
        for (int r = 0; r < 4; ++r) {
            const size_t row = (size_t)m0 + wm * 128 + mi * 16 + g4 + r;
            #pragma unroll
            for (int nj = 0; nj < 4; ++nj) {
                const int col = n0 + wn * 64 + nj * 16 + c15;
                const float v = acc[mi][nj][r] + bv[nj];
                if (F32OUT) ((float*)Cout)[row * (size_t)ldc + col] = v;
                else        ((short*)Cout)[row * (size_t)ldc + col] = f2bf(v);
            }
        }
    }
#undef STG_A
#undef STG_B
#undef LDA_
#undef LDB_
#undef MFMA4x4
}

// ---------------------------------------------------------------------------
// Per (head, block) causal attention on 128x128 tiles. qh/kh/vh: [16384][1024]
// bf16 (col = h*64+e). 4 waves x 32 q-rows.
// ---------------------------------------------------------------------------
__global__ __launch_bounds__(256) void attn_kernel(
    const short* __restrict__ qh, const short* __restrict__ kh,
    const short* __restrict__ vh, short* __restrict__ obuf)
{
    __shared__ __align__(16) char smem[54272];
    short* qs = (short*)smem;                 // [128][72]
    short* ks = (short*)smem + 9216;          // [128][72]
    short* vt = (short*)(smem + 36864);       // [64][136]  (vh transposed)
    short* ps = (short*)smem;                 // [128][136] (reuses qs+ks region)
    short* os = (short*)smem;                 // [128][72]  (reused post-PV)

    const int tid = threadIdx.x, lane = tid & 63, wid = tid >> 6;
    const int h = blockIdx.x, b = blockIdx.y;
    const size_t base = (size_t)b * 128 * 1024 + (size_t)h * 64;

    for (int i = tid; i < 1024; i += 256) {
        const int row = i >> 3, c8 = i & 7;
        const size_t g = base + (size_t)row * 1024 + c8 * 8;
        *(short8*)(qs + row * 72 + c8 * 8) = *(const short8*)(qh + g);
        *(short8*)(ks + row * 72 + c8 * 8) = *(const short8*)(kh + g);
        short8 vv = *(const short8*)(vh + g);
        #pragma unroll
        for (int j = 0; j < 8; ++j) vt[(c8 * 8 + j) * 136 + row] = vv[j];
    }
    __syncthreads();

    const int c15 = lane & 15, g8 = (lane >> 4) * 8, g4 = (lane >> 4) * 4;
    const int r0 = wid * 32;

    f32x4 sacc[2][8];
    #pragma unroll
    for (int mi = 0; mi < 2; ++mi)
        #pragma unroll
        for (int nj = 0; nj < 8; ++nj)
            sacc[mi][nj] = (f32x4){0.f, 0.f, 0.f, 0.f};
    #pragma unroll
    for (int kk = 0; kk < 2; ++kk) {
        short8 aq[2];
        #pragma unroll
        for (int mi = 0; mi < 2; ++mi)
            aq[mi] = *(const short8*)(qs + (r0 + mi * 16 + c15) * 72 + kk * 32 + g8);
        #pragma unroll
        for (int nj = 0; nj < 8; ++nj) {
            short8 bk8 = *(const short8*)(ks + (nj * 16 + c15) * 72 + kk * 32 + g8);
            #pragma unroll
            for (int mi = 0; mi < 2; ++mi)
                sacc[mi][nj] = __builtin_amdgcn_mfma_f32_16x16x32_bf16(
                    aq[mi], bk8, sacc[mi][nj], 0, 0, 0);
        }
    }
    __syncthreads();

    #pragma unroll
    for (int mi = 0; mi < 2; ++mi) {
        #pragma unroll
        for (int r = 0; r < 4; ++r) {
            const int qrow = r0 + mi * 16 + g4 + r;
            float m = -3.0e38f, pv[8];
            #pragma unroll
            for (int nj = 0; nj < 8; ++nj) {
                float s = sacc[mi][nj][r] * 0.125f;
                if (nj * 16 + c15 > qrow) s = -1.0e9f;
                pv[nj] = s; m = fmaxf(m, s);
            }
            #pragma unroll
            for (int off = 8; off >= 1; off >>= 1) m = fmaxf(m, __shfl_xor(m, off));
            float sum = 0.f;
            #pragma unroll
            for (int nj = 0; nj < 8; ++nj) { float p = __expf(pv[nj] - m); pv[nj] = p; sum += p; }
            #pragma unroll
            for (int off = 8; off >= 1; off >>= 1) sum += __shfl_xor(sum, off);
            const float inv = 1.0f / sum;
            #pragma unroll
            for (int nj = 0; nj < 8; ++nj)
                ps[qrow * 136 + nj * 16 + c15] = f2bf(pv[nj] * inv);
        }
    }
    __syncthreads();

    f32x4 oacc[2][4];
    #pragma unroll
    for (int mi = 0; mi < 2; ++mi)
        #pragma unroll
        for (int nj = 0; nj < 4; ++nj)
            oacc[mi][nj] = (f32x4){0.f, 0.f, 0.f, 0.f};
    #pragma unroll
    for (int kt = 0; kt < 4; ++kt) {
        short8 ap[2];
        #pragma unroll
        for (int mi = 0; mi < 2; ++mi)
            ap[mi] = *(const short8*)(ps + (r0 + mi * 16 + c15) * 136 + kt * 32 + g8);
        #pragma unroll
        for (int nj = 0; nj < 4; ++nj) {
            short8 bv8 = *(const short8*)(vt + (nj * 16 + c15) * 136 + kt * 32 + g8);
            #pragma unroll
            for (int mi = 0; mi < 2; ++mi)
                oacc[mi][nj] = __builtin_amdgcn_mfma_f32_16x16x32_bf16(
                    ap[mi], bv8, oacc[mi][nj], 0, 0, 0);
        }
    }
    __syncthreads();

    #pragma unroll
    for (int mi = 0; mi < 2; ++mi)
        #pragma unroll
        for (int r = 0; r < 4; ++r)
            #pragma unroll
            for (int nj = 0; nj < 4; ++nj)
                os[(r0 + mi * 16 + g4 + r) * 72 + nj * 16 + c15] = f2bf(oacc[mi][nj][r]);
    __syncthreads();

    for (int i = tid; i < 1024; i += 256) {
        const int row = i >> 3, c8 = i & 7;
        *(short8*)(obuf + base + (size_t)row * 1024 + c8 * 8) =
            *(const short8*)(os + row * 72 + c8 * 8);
    }
}

// ---------------------------------------------------------------------------
__global__ void pad_convert_inputs(const float* __restrict__ in, short* __restrict__ out)
{
    const int row = blockIdx.x;                 // [0, 16388)
    const int n = row / 8194, l = row % 8194;
    short* orow = out + (size_t)row * 4096;
    if (l == 0 || l == 8193) {
        for (int i = threadIdx.x; i < 512; i += 256) {
            uint4 z; z.x = z.y = z.z = z.w = 0u;
            *(uint4*)(orow + i * 8) = z;
        }
    } else {
        const float* irow = in + ((size_t)n * 8192 + (l - 1)) * 4096;
        for (int i = threadIdx.x; i < 512; i += 256) {
            float4 a = *(const float4*)(irow + i * 8);
            float4 b = *(const float4*)(irow + i * 8 + 4);
            short8 v;
            v[0] = f2bf(a.x); v[1] = f2bf(a.y); v[2] = f2bf(a.z); v[3] = f2bf(a.w);
            v[4] = f2bf(b.x); v[5] = f2bf(b.y); v[6] = f2bf(b.z); v[7] = f2bf(b.w);
            *(short8*)(orow + i * 8) = v;
        }
    }
}

__global__ void transpose_convert(const float* __restrict__ in, short* __restrict__ out,
                                  int R, int C)
{
    __shared__ float tile[32][33];
    const int tx = threadIdx.x & 31, ty = threadIdx.x >> 5;   // 32 x 8
    const int bx = blockIdx.x * 32, by = blockIdx.y * 32;
    #pragma unroll
    for (int i = 0; i < 32; i += 8)
        tile[ty + i][tx] = in[(size_t)(by + ty + i) * C + bx + tx];
    __syncthreads();
    #pragma unroll
    for (int i = 0; i < 32; i += 8)
        out[(size_t)(bx + ty + i) * R + by + tx] = f2bf(tile[tx][ty + i]);
}

__global__ void convert_bf16(const float* __restrict__ in, short* __restrict__ out, int n8)
{
    const int idx = blockIdx.x * 256 + threadIdx.x;
    if (idx < n8) {
        float4 a = *(const float4*)(in + (size_t)idx * 8);
        float4 b = *(const float4*)(in + (size_t)idx * 8 + 4);
        short8 v;
        v[0] = f2bf(a.x); v[1] = f2bf(a.y); v[2] = f2bf(a.z); v[3] = f2bf(a.w);
        v[4] = f2bf(b.x); v[5] = f2bf(b.y); v[6] = f2bf(b.z); v[7] = f2bf(b.w);
        *(short8*)(out + (size_t)idx * 8) = v;
    }
}

__global__ void fuse_bias(const float* __restrict__ bo, const float* __restrict__ projw,
                          const float* __restrict__ projb, float* __restrict__ outb)
{
    const int j = blockIdx.x * 256 + threadIdx.x;   // 4096
    float s = projb[j];
    for (int w = 0; w < 1024; ++w) s = fmaf(bo[w], projw[(size_t)w * 4096 + j], s);
    outb[j] = s;
}

// ---------------------------------------------------------------------------
extern "C" void kernel_launch(void* const* d_in, const int* in_sizes, int n_in,
                              void* d_out, int out_size, void* d_ws, size_t ws_size,
                              hipStream_t stream)
{
    const float* inputs = (const float*)d_in[0];
    const float* conv_w = (const float*)d_in[1];
    const float* conv_b = (const float*)d_in[2];
    const float* wq     = (const float*)d_in[3];
    const float* bq     = (const float*)d_in[4];
    const float* wk     = (const float*)d_in[5];
    const float* bk     = (const float*)d_in[6];
    const float* wv     = (const float*)d_in[7];
    const float* bv     = (const float*)d_in[8];
    const float* wo     = (const float*)d_in[9];
    const float* bo     = (const float*)d_in[10];
    const float* proj_w = (const float*)d_in[11];
    const float* proj_b = (const float*)d_in[12];

    char* ws = (char*)d_ws;
    short* in_pad = (short*)(ws + 0);             // [2][8194][4096]
    short* w_bf   = (short*)(ws + 134283264);     // [3][3072][4096] BT
    short* qkv    = (short*)(ws + 209780736);     // [16384][3072]
    short* wq_t   = (short*)(ws + 310444032);     // [1024][1024] BT
    short* wk_t   = (short*)(ws + 312541184);
    short* wv_t   = (short*)(ws + 314638336);
    short* wo_bf  = (short*)(ws + 316735488);     // [1024][1024]
    short* proj_t = (short*)(ws + 318832640);     // [4096][1024]
    short* WfT    = (short*)(ws + 327221248);     // [4096][1024]
    float* bfused = (float*)(ws + 335609856);     // [4096]
    short* qh_buf = (short*)(ws + 0);             // over in_pad
    short* kh_buf = (short*)(ws + 33554432);
    short* vh_buf = (short*)(ws + 67108864);
    short* o_buf  = (short*)(ws + 134283264);     // over w_bf

    dim3 blk(256), blk5(512);

    pad_convert_inputs<<<16388, blk, 0, stream>>>(inputs, in_pad);
    for (int t = 0; t < 3; ++t)
        transpose_convert<<<dim3(96, 128), blk, 0, stream>>>(
            conv_w + (size_t)t * 4096 * 3072, w_bf + (size_t)t * 3072 * 4096, 4096, 3072);
    transpose_convert<<<dim3(32, 32), blk, 0, stream>>>(wq, wq_t, 1024, 1024);
    transpose_convert<<<dim3(32, 32), blk, 0, stream>>>(wk, wk_t, 1024, 1024);
    transpose_convert<<<dim3(32, 32), blk, 0, stream>>>(wv, wv_t, 1024, 1024);
    transpose_convert<<<dim3(128, 32), blk, 0, stream>>>(proj_w, proj_t, 1024, 4096);
    convert_bf16<<<512, blk, 0, stream>>>(wo, wo_bf, 131072);
    fuse_bias<<<16, blk, 0, stream>>>(bo, proj_w, proj_b, bfused);

    // WfT[dm][he] = sum_w proj_t[dm][w] * wo_flat[he][w]
    gemm256<1, false><<<dim3(4, 16), blk5, 0, stream>>>(
        proj_t, 1024, wo_bf, 1024, 0, WfT, 1024, nullptr, 16);
    // conv as 3-tap GEMM
    gemm256<3, false><<<dim3(12, 64), blk5, 0, stream>>>(
        in_pad, 4096, w_bf, 4096, (long long)3072 * 4096, qkv, 3072, conv_b, 192);
    // head projections
    gemm256<1, false><<<dim3(4, 64), blk5, 0, stream>>>(
        qkv + 0,    3072, wq_t, 1024, 0, qh_buf, 1024, bq, 16);
    gemm256<1, false><<<dim3(4, 64), blk5, 0, stream>>>(
        qkv + 1024, 3072, wk_t, 1024, 0, kh_buf, 1024, bk, 16);
    gemm256<1, false><<<dim3(4, 64), blk5, 0, stream>>>(
        qkv + 2048, 3072, wv_t, 1024, 0, vh_buf, 1024, bv, 16);

    attn_kernel<<<dim3(16, 128), blk, 0, stream>>>(qh_buf, kh_buf, vh_buf, o_buf);

    // out = o @ Wf + bfused   (f32 out)
    gemm256<1, true><<<dim3(16, 64), blk5, 0, stream>>>(
        o_buf, 1024, WfT, 1024, 0, d_out, 4096, bfused, 16);
}